// Round 6
// baseline (74.594 us; speedup 1.0000x reference)
//
#include <hip/hip_runtime.h>
#include <hip/hip_bf16.h>

// Causal MHA forward: S=2048, H=16, D=128, fp32 in/out, bf16 MFMA internally.
// Prepass: K -> bf16 [h][s][d], V -> bf16 transposed [h][d][s] into d_ws.
// Main: split-K flash attention with uniform-duration blocks:
//   pair j: qtA=31-j, qtB=j. Block X: qtA k-chunks 0..15 (16). Block Y: qtA
//   k-chunks 16..qtA (16-j) then qtB all (j+1) = 17. Additive fixed-bound
//   softmax (p=exp(s-14)) makes k-split partials summable. X / Y-seg1 write
//   unnormalized O,l partials to ws; combine kernel merges qtA tiles.
#define S_LEN 2048
#define NH 16
#define HD 128
#define QBLK 64
#define KBLK 64
#define SM_BOUND 14.0f

typedef short short8 __attribute__((ext_vector_type(8)));
typedef float f32x4 __attribute__((ext_vector_type(4)));

__device__ __forceinline__ ushort f2bf(float f) {
  union { float f; unsigned u; } v; v.f = f;
  unsigned u = v.u;
  return (ushort)((u + 0x7fffu + ((u >> 16) & 1u)) >> 16);  // RNE
}

// global (AS1) -> LDS (AS3) direct 16B load; source pre-swizzled, dest linear.
#define GLDS(gp, lp)                                                      \
  __builtin_amdgcn_global_load_lds(                                       \
      (const __attribute__((address_space(1))) void*)(gp),                \
      (__attribute__((address_space(3))) void*)(lp), 16, 0, 0)

// ---------------- prepass: convert + transpose ----------------
__global__ __launch_bounds__(256)
void prep(const float* __restrict__ Kg, const float* __restrict__ Vg,
          ushort* __restrict__ Kb, ushort* __restrict__ Vb) {
  __shared__ ushort lt[64 * HD];  // 16 KB, swizzled
  const int tid = threadIdx.x;
  const int h = blockIdx.x & 15;
  const int j0 = (blockIdx.x >> 4) * 64;

#pragma unroll
  for (int it = 0; it < 8; ++it) {
    int flat = it * 256 + tid;       // float4 index over 64x32
    int r = flat >> 5, d4 = (flat & 31) * 4;
    float4 v = *(const float4*)(Kg + ((size_t)(j0 + r) * NH + h) * HD + d4);
    ushort4 b;
    b.x = f2bf(v.x); b.y = f2bf(v.y); b.z = f2bf(v.z); b.w = f2bf(v.w);
    *(ushort4*)(Kb + ((size_t)h * S_LEN + j0 + r) * HD + d4) = b;
  }
#pragma unroll
  for (int it = 0; it < 8; ++it) {
    int flat = it * 256 + tid;
    int r = flat >> 5, d4 = (flat & 31) * 4;
    float4 v = *(const float4*)(Vg + ((size_t)(j0 + r) * NH + h) * HD + d4);
    ushort4 b;
    b.x = f2bf(v.x); b.y = f2bf(v.y); b.z = f2bf(v.z); b.w = f2bf(v.w);
    *(ushort4*)(&lt[r * 128 + (d4 ^ ((r & 7) << 3))]) = b;
  }
  __syncthreads();
  const int d = tid >> 1, half = tid & 1;
  ushort vals[32];
#pragma unroll
  for (int j = 0; j < 32; ++j) {
    int jj = half * 32 + j;
    vals[j] = lt[jj * 128 + (d ^ ((jj & 7) << 3))];
  }
  ushort* dst = Vb + ((size_t)h * HD + d) * S_LEN + j0 + half * 32;
#pragma unroll
  for (int q = 0; q < 4; ++q) {
    short8 w;
#pragma unroll
    for (int e = 0; e < 8; ++e) w[e] = (short)vals[q * 8 + e];
    *(short8*)(dst + q * 8) = w;
  }
}

// one k-chunk of the two-role scheme. QFR must be a token naming a
// short8[2][4] register array (static indexing; rule #20).
#define CHUNK_BODY(QFR, QB_, QT_CUR, KC, KC_NEXT)                              \
  do {                                                                         \
    const int b_ = idx & 1;                                                    \
    if ((KC_NEXT) >= 0) stage(b_ ^ 1, (KC_NEXT));                              \
    const ushort* lk = lds_k[b_];                                              \
    f32x4 sacc0 = (f32x4){0.f, 0.f, 0.f, 0.f};                                 \
    f32x4 sacc1 = (f32x4){0.f, 0.f, 0.f, 0.f};                                 \
    const int krow = kh * 16 + lr;                                             \
    __builtin_amdgcn_s_setprio(1);                                             \
    _Pragma("unroll")                                                          \
    for (int dk = 0; dk < 4; ++dk) {                                           \
      short8 kf = *(const short8*)&lk[krow * 128 +                             \
                                      ((dk * 32 + lg * 8) ^ ((lr & 7) << 3))]; \
      sacc0 = __builtin_amdgcn_mfma_f32_16x16x32_bf16(kf, QFR[0][dk], sacc0, 0, 0, 0); \
      sacc1 = __builtin_amdgcn_mfma_f32_16x16x32_bf16(kf, QFR[1][dk], sacc1, 0, 0, 0); \
    }                                                                          \
    __builtin_amdgcn_s_setprio(0);                                             \
    float p[2][4];                                                             \
    if ((KC) == (QT_CUR)) {                                                    \
      const int k0_ = (KC) * KBLK;                                             \
      _Pragma("unroll")                                                        \
      for (int i = 0; i < 4; ++i) {                                            \
        float e0 = __expf(sacc0[i] - SM_BOUND);                                \
        float e1 = __expf(sacc1[i] - SM_BOUND);                                \
        int kg = k0_ + kh * 16 + lg * 4 + i;                                   \
        p[0][i] = (kg > (QB_) + qf * 32 + lr) ? 0.f : e0;                      \
        p[1][i] = (kg > (QB_) + qf * 32 + 16 + lr) ? 0.f : e1;                 \
      }                                                                        \
    } else {                                                                   \
      _Pragma("unroll")                                                        \
      for (int i = 0; i < 4; ++i) {                                            \
        p[0][i] = __expf(sacc0[i] - SM_BOUND);                                 \
        p[1][i] = __expf(sacc1[i] - SM_BOUND);                                 \
      }                                                                        \
    }                                                                          \
    l_run[0] += (p[0][0] + p[0][1]) + (p[0][2] + p[0][3]);                     \
    l_run[1] += (p[1][0] + p[1][1]) + (p[1][2] + p[1][3]);                     \
    _Pragma("unroll")                                                          \
    for (int qc = 0; qc < 2; ++qc) {                                           \
      int q_ = qf * 32 + qc * 16 + lr;                                         \
      _Pragma("unroll")                                                        \
      for (int ip = 0; ip < 2; ++ip) {                                         \
        unsigned w_;                                                           \
        asm("v_cvt_pk_bf16_f32 %0, %1, %2" : "=v"(w_)                          \
            : "v"(p[qc][2 * ip]), "v"(p[qc][2 * ip + 1]));                     \
        int k_ = kh * 16 + lg * 4 + 2 * ip;                                    \
        *(unsigned*)&lds_p[q_ * 64 + (k_ ^ ((q_ & 7) << 3))] = w_;             \
      }                                                                        \
    }                                                                          \
    __syncthreads();                                                           \
    const ushort* lv = lds_vt[b_];                                             \
    short8 pa0[2], pa1[2];                                                     \
    {                                                                          \
      int q_ = qf * 32 + lr;                                                   \
      pa0[0] = *(const short8*)&lds_p[q_ * 64 + ((lg * 8) ^ ((q_ & 7) << 3))]; \
      pa0[1] = *(const short8*)&lds_p[q_ * 64 + ((32 + lg * 8) ^ ((q_ & 7) << 3))]; \
      q_ += 16;                                                                \
      pa1[0] = *(const short8*)&lds_p[q_ * 64 + ((lg * 8) ^ ((q_ & 7) << 3))]; \
      pa1[1] = *(const short8*)&lds_p[q_ * 64 + ((32 + lg * 8) ^ ((q_ & 7) << 3))]; \
    }                                                                          \
    __builtin_amdgcn_s_setprio(1);                                             \
    _Pragma("unroll")                                                          \
    for (int dt = 0; dt < 2; ++dt) {                                           \
      int d_ = dh * 32 + dt * 16 + lr;                                         \
      _Pragma("unroll")                                                        \
      for (int ks = 0; ks < 2; ++ks) {                                         \
        short8 vf = *(const short8*)&lv[d_ * 64 +                              \
                                        ((ks * 32 + lg * 8) ^ ((d_ & 7) << 3))]; \
        oacc[0][dt] = __builtin_amdgcn_mfma_f32_16x16x32_bf16(pa0[ks], vf, oacc[0][dt], 0, 0, 0); \
        oacc[1][dt] = __builtin_amdgcn_mfma_f32_16x16x32_bf16(pa1[ks], vf, oacc[1][dt], 0, 0, 0); \
      }                                                                        \
    }                                                                          \
    __builtin_amdgcn_s_setprio(0);                                             \
    asm volatile("s_waitcnt vmcnt(0)" ::: "memory");                           \
    __syncthreads();                                                           \
  } while (0)

// ---------------- split main kernel: uniform 16/17-chunk blocks ----------------
__global__ __launch_bounds__(512, 4)
void attn_split(const float* __restrict__ Qg, const ushort* __restrict__ Kb,
                const ushort* __restrict__ Vb, float* __restrict__ Og,
                float* __restrict__ Opart, float* __restrict__ lpart) {
  __shared__ ushort lds_k[2][KBLK * HD];    // 2 x 16 KB, [64 k][128 d] swizzled
  __shared__ ushort lds_vt[2][HD * KBLK];   // 2 x 16 KB, [128 d][64 k] swizzled
  __shared__ ushort lds_p[QBLK * KBLK];     // 8 KB, [64 q][64 k] swizzled
  __shared__ float  lsc[2][4][2][16];       // l partials [qf][kh][qc][lr]

  const int tid = threadIdx.x;
  const int l   = tid & 63;
  const int wv  = tid >> 6;      // 0..7
  const int qf  = wv >> 2;       // q 32-row group
  const int kh  = wv & 3;        // phase A: k 16-row quarter
  const int dh  = wv & 3;        // phase B: d 32-col quarter
  const int lr  = l & 15;
  const int lg  = l >> 4;

  const int bid = blockIdx.x;
  const int h   = bid >> 5;
  const int s   = bid & 31;
  const bool roleY = (s >= 16);
  const int jj  = s & 15;
  const int qtA = 31 - jj;
  const int pid = h * 16 + jj;

  const ushort* khp = Kb + (size_t)h * S_LEN * HD;
  const ushort* vhp = Vb + (size_t)h * HD * S_LEN;

  // per-thread pre-swizzled staging source offsets (LDS dest linear, rule #21)
  const int b0 = tid, b1 = 512 + tid;
  const int r0 = b0 >> 4, r1 = b1 >> 4;
  const int koff0 = r0 * 128 + (((b0 & 15) ^ (r0 & 7)) << 3);
  const int koff1 = r1 * 128 + (((b1 & 15) ^ (r1 & 7)) << 3);
  const int dd0 = b0 >> 3, dd1 = b1 >> 3;
  const int voff0 = dd0 * S_LEN + (((b0 & 7) ^ (dd0 & 7)) << 3);
  const int voff1 = dd1 * S_LEN + (((b1 & 7) ^ (dd1 & 7)) << 3);

  auto stage = [&](int buf, int kc) {
    const ushort* kbase = khp + kc * (KBLK * HD);
    GLDS(kbase + koff0, &lds_k[buf][tid * 8]);
    GLDS(kbase + koff1, &lds_k[buf][4096 + tid * 8]);
    const ushort* vbase = vhp + kc * KBLK;
    GLDS(vbase + voff0, &lds_vt[buf][tid * 8]);
    GLDS(vbase + voff1, &lds_vt[buf][4096 + tid * 8]);
  };

  const int seg1  = roleY ? (16 - jj) : 16;
  const int total = roleY ? 17 : 16;

  stage(0, roleY ? 16 : 0);

  // Q fragments (B-operand), scale folded in. X: qtA only; Y: qtA + qtB.
  const float scale = 0.08838834764831845f;  // 1/sqrt(128)
  short8 qA[2][4], qB[2][4];
  auto loadQ = [&](short8 (&dst)[2][4], int qb) {
#pragma unroll
    for (int qc = 0; qc < 2; ++qc) {
      const float* qsrc = Qg + ((size_t)(qb + qf * 32 + qc * 16 + lr) * NH + h) * HD;
#pragma unroll
      for (int dk = 0; dk < 4; ++dk) {
        float4 a = *(const float4*)(qsrc + dk * 32 + lg * 8);
        float4 b2 = *(const float4*)(qsrc + dk * 32 + lg * 8 + 4);
        short8 f;
        f[0] = (short)f2bf(a.x * scale);  f[1] = (short)f2bf(a.y * scale);
        f[2] = (short)f2bf(a.z * scale);  f[3] = (short)f2bf(a.w * scale);
        f[4] = (short)f2bf(b2.x * scale); f[5] = (short)f2bf(b2.y * scale);
        f[6] = (short)f2bf(b2.z * scale); f[7] = (short)f2bf(b2.w * scale);
        dst[qc][dk] = f;
      }
    }
  };
  loadQ(qA, qtA * 64);
  if (roleY) loadQ(qB, jj * 64);

  f32x4 oacc[2][2];
#pragma unroll
  for (int qc = 0; qc < 2; ++qc)
#pragma unroll
    for (int dt = 0; dt < 2; ++dt) oacc[qc][dt] = (f32x4){0.f, 0.f, 0.f, 0.f};
  float l_run[2] = {0.f, 0.f};

  // unnormalized partial writer (additive across blocks)
  auto write_partial = [&](int slot) {
    float t0 = l_run[0], t1 = l_run[1];
    t0 += __shfl_xor(t0, 16, 64); t0 += __shfl_xor(t0, 32, 64);
    t1 += __shfl_xor(t1, 16, 64); t1 += __shfl_xor(t1, 32, 64);
    if (lg == 0) { lsc[qf][kh][0][lr] = t0; lsc[qf][kh][1][lr] = t1; }
    __syncthreads();
    if (kh == 0 && lg == 0) {
#pragma unroll
      for (int qc = 0; qc < 2; ++qc) {
        float sl = (lsc[qf][0][qc][lr] + lsc[qf][1][qc][lr]) +
                   (lsc[qf][2][qc][lr] + lsc[qf][3][qc][lr]);
        lpart[(size_t)(pid * 2 + slot) * 64 + qf * 32 + qc * 16 + lr] = sl;
      }
    }
    float* so = Opart + (size_t)(pid * 2 + slot) * 8192;
#pragma unroll
    for (int qc = 0; qc < 2; ++qc)
#pragma unroll
      for (int dt = 0; dt < 2; ++dt)
#pragma unroll
        for (int i = 0; i < 4; ++i)
          so[(qf * 32 + qc * 16 + lg * 4 + i) * 128 + dh * 32 + dt * 16 + lr] =
              oacc[qc][dt][i];
  };

  asm volatile("s_waitcnt vmcnt(0)" ::: "memory");
  __syncthreads();

  int idx = 0;
  // ---- segment 1: tile qtA ----
  for (; idx < seg1; ++idx) {
    const int kc = roleY ? (16 + idx) : idx;
    const int kcn = (idx + 1 < seg1) ? (kc + 1) : (roleY ? 0 : -1);
    CHUNK_BODY(qA, qtA * 64, qtA, kc, kcn);
  }

  if (!roleY) {
    write_partial(0);
    return;
  }

  // ---- Y: flush qtA partial, reset, run tile qtB ----
  write_partial(1);
#pragma unroll
  for (int qc = 0; qc < 2; ++qc)
#pragma unroll
    for (int dt = 0; dt < 2; ++dt) oacc[qc][dt] = (f32x4){0.f, 0.f, 0.f, 0.f};
  l_run[0] = 0.f; l_run[1] = 0.f;
  __syncthreads();

  for (; idx < total; ++idx) {
    const int kc = idx - seg1;
    const int kcn = (idx + 1 < total) ? (kc + 1) : -1;
    CHUNK_BODY(qB, jj * 64, jj, kc, kcn);
  }

  // ---- direct epilogue for qtB (Y owns all of it) ----
  l_run[0] += __shfl_xor(l_run[0], 16, 64); l_run[0] += __shfl_xor(l_run[0], 32, 64);
  l_run[1] += __shfl_xor(l_run[1], 16, 64); l_run[1] += __shfl_xor(l_run[1], 32, 64);
  if (lg == 0) { lsc[qf][kh][0][lr] = l_run[0]; lsc[qf][kh][1][lr] = l_run[1]; }
  __syncthreads();
  float inv[2][4];
#pragma unroll
  for (int qc = 0; qc < 2; ++qc)
#pragma unroll
    for (int i = 0; i < 4; ++i) {
      int q15 = lg * 4 + i;
      float sl = (lsc[qf][0][qc][q15] + lsc[qf][1][qc][q15]) +
                 (lsc[qf][2][qc][q15] + lsc[qf][3][qc][q15]);
      inv[qc][i] = 1.0f / sl;
    }
  const int qbaseB = jj * 64;
#pragma unroll
  for (int qc = 0; qc < 2; ++qc)
#pragma unroll
    for (int dt = 0; dt < 2; ++dt)
#pragma unroll
      for (int i = 0; i < 4; ++i) {
        int qg = qbaseB + qf * 32 + qc * 16 + lg * 4 + i;
        Og[((size_t)qg * NH + h) * HD + dh * 32 + dt * 16 + lr] =
            oacc[qc][dt][i] * inv[qc][i];
      }
}

// ---------------- combine: merge the two qtA partials per pair ----------------
__global__ __launch_bounds__(256)
void combine(const float* __restrict__ Opart, const float* __restrict__ lpart,
             float* __restrict__ Og) {
  const int pid = blockIdx.x;           // 0..255 = h*16 + j
  const int h = pid >> 4, jj = pid & 15;
  const int qbase = (31 - jj) * 64;
  const int t = threadIdx.x;
  const int q = t >> 2, d0 = (t & 3) * 32;
  const float* p0 = Opart + (size_t)(pid * 2) * 8192 + q * 128 + d0;
  const float* p1 = p0 + 8192;
  const float lsum = lpart[(size_t)(pid * 2) * 64 + q] +
                     lpart[(size_t)(pid * 2 + 1) * 64 + q];
  const float inv = 1.0f / lsum;
  float* og = Og + ((size_t)(qbase + q) * NH + h) * HD + d0;
#pragma unroll
  for (int e = 0; e < 32; e += 4) {
    float4 a = *(const float4*)(p0 + e);
    float4 b = *(const float4*)(p1 + e);
    float4 o;
    o.x = (a.x + b.x) * inv; o.y = (a.y + b.y) * inv;
    o.z = (a.z + b.z) * inv; o.w = (a.w + b.w) * inv;
    *(float4*)(og + e) = o;
  }
}

// ---------------- legacy round-5 kernel (fallback if ws too small) ----------------
__global__ __launch_bounds__(512, 4)
void attn_fwd4(const float* __restrict__ Qg, const ushort* __restrict__ Kb,
               const ushort* __restrict__ Vb, float* __restrict__ Og) {
  __shared__ ushort lds_k[2][KBLK * HD];
  __shared__ ushort lds_vt[2][HD * KBLK];
  __shared__ ushort lds_p[QBLK * KBLK];
  __shared__ float  lsc[2][4][2][16];

  const int tid = threadIdx.x;
  const int l   = tid & 63;
  const int wv  = tid >> 6;
  const int qf  = wv >> 2;
  const int kh  = wv & 3;
  const int dh  = wv & 3;
  const int lr  = l & 15;
  const int lg  = l >> 4;

  const int bid = blockIdx.x;
  const int h  = bid & 15;
  const int qi = bid >> 4;
  const int qt = (qi < 16) ? (31 - 2 * qi) : (2 * (qi - 16));
  const int qbase = qt * QBLK;
  const int nch = qt + 1;

  const ushort* khp = Kb + (size_t)h * S_LEN * HD;
  const ushort* vhp = Vb + (size_t)h * HD * S_LEN;

  const ushort *kp0, *kp1, *vp0, *vp1;
  {
    int b0 = tid, b1 = 512 + tid;
    int r0 = b0 >> 4, r1 = b1 >> 4;
    kp0 = khp + r0 * 128 + (((b0 & 15) ^ (r0 & 7)) << 3);
    kp1 = khp + r1 * 128 + (((b1 & 15) ^ (r1 & 7)) << 3);
    int d0 = b0 >> 3, d1 = b1 >> 3;
    vp0 = vhp + (size_t)d0 * S_LEN + (((b0 & 7) ^ (d0 & 7)) << 3);
    vp1 = vhp + (size_t)d1 * S_LEN + (((b1 & 7) ^ (d1 & 7)) << 3);
  }
  auto stage = [&](int buf) {
    ushort* kd = lds_k[buf];
    GLDS(kp0, kd + tid * 8);
    GLDS(kp1, kd + 4096 + tid * 8);
    ushort* vd = lds_vt[buf];
    GLDS(vp0, vd + tid * 8);
    GLDS(vp1, vd + 4096 + tid * 8);
    kp0 += KBLK * HD; kp1 += KBLK * HD;
    vp0 += KBLK;      vp1 += KBLK;
  };

  stage(0);

  const float scale = 0.08838834764831845f;
  short8 qfr[2][4];
#pragma unroll
  for (int qc = 0; qc < 2; ++qc) {
    const float* qsrc = Qg + ((size_t)(qbase + qf * 32 + qc * 16 + lr) * NH + h) * HD;
#pragma unroll
    for (int dk = 0; dk < 4; ++dk) {
      float4 a = *(const float4*)(qsrc + dk * 32 + lg * 8);
      float4 b2 = *(const float4*)(qsrc + dk * 32 + lg * 8 + 4);
      short8 f;
      f[0] = (short)f2bf(a.x * scale);  f[1] = (short)f2bf(a.y * scale);
      f[2] = (short)f2bf(a.z * scale);  f[3] = (short)f2bf(a.w * scale);
      f[4] = (short)f2bf(b2.x * scale); f[5] = (short)f2bf(b2.y * scale);
      f[6] = (short)f2bf(b2.z * scale); f[7] = (short)f2bf(b2.w * scale);
      qfr[qc][dk] = f;
    }
  }

  f32x4 oacc[2][2];
#pragma unroll
  for (int qc = 0; qc < 2; ++qc)
#pragma unroll
    for (int dt = 0; dt < 2; ++dt) oacc[qc][dt] = (f32x4){0.f, 0.f, 0.f, 0.f};
  float l_run[2] = {0.f, 0.f};

  asm volatile("s_waitcnt vmcnt(0)" ::: "memory");
  __syncthreads();

  for (int c = 0; c < nch; ++c) {
    const int b = c & 1;
    if (c + 1 < nch) stage(b ^ 1);

    const ushort* lk = lds_k[b];
    f32x4 sacc[2];
    sacc[0] = (f32x4){0.f, 0.f, 0.f, 0.f};
    sacc[1] = (f32x4){0.f, 0.f, 0.f, 0.f};
    const int krow = kh * 16 + lr;
#pragma unroll
    for (int dk = 0; dk < 4; ++dk) {
      short8 kf = *(const short8*)&lk[krow * 128 + ((dk * 32 + lg * 8) ^ ((lr & 7) << 3))];
      sacc[0] = __builtin_amdgcn_mfma_f32_16x16x32_bf16(kf, qfr[0][dk], sacc[0], 0, 0, 0);
      sacc[1] = __builtin_amdgcn_mfma_f32_16x16x32_bf16(kf, qfr[1][dk], sacc[1], 0, 0, 0);
    }

    float p[2][4];
    if (c == nch - 1) {
      const int k0 = c * KBLK;
#pragma unroll
      for (int qc = 0; qc < 2; ++qc) {
        int qg = qbase + qf * 32 + qc * 16 + lr;
#pragma unroll
        for (int i = 0; i < 4; ++i) {
          float e = __expf(sacc[qc][i] - SM_BOUND);
          int kg = k0 + kh * 16 + lg * 4 + i;
          p[qc][i] = (kg > qg) ? 0.f : e;
        }
      }
    } else {
#pragma unroll
      for (int qc = 0; qc < 2; ++qc)
#pragma unroll
        for (int i = 0; i < 4; ++i)
          p[qc][i] = __expf(sacc[qc][i] - SM_BOUND);
    }
#pragma unroll
    for (int qc = 0; qc < 2; ++qc)
      l_run[qc] += (p[qc][0] + p[qc][1]) + (p[qc][2] + p[qc][3]);

#pragma unroll
    for (int qc = 0; qc < 2; ++qc) {
      int q = qf * 32 + qc * 16 + lr;
#pragma unroll
      for (int ip = 0; ip < 2; ++ip) {
        unsigned w;
        asm("v_cvt_pk_bf16_f32 %0, %1, %2"
            : "=v"(w) : "v"(p[qc][2 * ip]), "v"(p[qc][2 * ip + 1]));
        int k = kh * 16 + lg * 4 + 2 * ip;
        *(unsigned*)&lds_p[q * 64 + (k ^ ((q & 7) << 3))] = w;
      }
    }
    __syncthreads();

    const ushort* lv = lds_vt[b];
    short8 pa[2][2];
#pragma unroll
    for (int qc = 0; qc < 2; ++qc) {
      int q = qf * 32 + qc * 16 + lr;
#pragma unroll
      for (int ks = 0; ks < 2; ++ks)
        pa[qc][ks] = *(const short8*)&lds_p[q * 64 + ((ks * 32 + lg * 8) ^ ((q & 7) << 3))];
    }
#pragma unroll
    for (int dt = 0; dt < 2; ++dt) {
      int d = dh * 32 + dt * 16 + lr;
#pragma unroll
      for (int ks = 0; ks < 2; ++ks) {
        short8 vf = *(const short8*)&lv[d * 64 + ((ks * 32 + lg * 8) ^ ((d & 7) << 3))];
        oacc[0][dt] = __builtin_amdgcn_mfma_f32_16x16x32_bf16(pa[0][ks], vf, oacc[0][dt], 0, 0, 0);
        oacc[1][dt] = __builtin_amdgcn_mfma_f32_16x16x32_bf16(pa[1][ks], vf, oacc[1][dt], 0, 0, 0);
      }
    }

    asm volatile("s_waitcnt vmcnt(0)" ::: "memory");
    __syncthreads();
  }

#pragma unroll
  for (int qc = 0; qc < 2; ++qc) {
    l_run[qc] += __shfl_xor(l_run[qc], 16, 64);
    l_run[qc] += __shfl_xor(l_run[qc], 32, 64);
  }
  if (lg == 0) {
    lsc[qf][kh][0][lr] = l_run[0];
    lsc[qf][kh][1][lr] = l_run[1];
  }
  __syncthreads();
  float inv[2][4];
#pragma unroll
  for (int qc = 0; qc < 2; ++qc)
#pragma unroll
    for (int i = 0; i < 4; ++i) {
      int q15 = lg * 4 + i;
      float sl = (lsc[qf][0][qc][q15] + lsc[qf][1][qc][q15]) +
                 (lsc[qf][2][qc][q15] + lsc[qf][3][qc][q15]);
      inv[qc][i] = 1.0f / sl;
    }
#pragma unroll
  for (int qc = 0; qc < 2; ++qc)
#pragma unroll
    for (int dt = 0; dt < 2; ++dt)
#pragma unroll
      for (int i = 0; i < 4; ++i) {
        int qg = qbase + qf * 32 + qc * 16 + lg * 4 + i;
        Og[((size_t)qg * NH + h) * HD + dh * 32 + dt * 16 + lr] =
            oacc[qc][dt][i] * inv[qc][i];
      }
}

extern "C" void kernel_launch(void* const* d_in, const int* in_sizes, int n_in,
                              void* d_out, int out_size, void* d_ws, size_t ws_size,
                              hipStream_t stream) {
  (void)in_sizes; (void)n_in; (void)out_size;
  const float* Q = (const float*)d_in[0];
  const float* K = (const float*)d_in[1];
  const float* V = (const float*)d_in[2];
  float* O = (float*)d_out;

  const size_t elems = (size_t)S_LEN * NH * HD;            // 4M
  const size_t needKV = 2 * elems * sizeof(ushort);        // 16 MB
  const size_t oPartB = (size_t)256 * 2 * 8192 * 4;        // 16 MB
  const size_t lPartB = (size_t)256 * 2 * 64 * 4;          // 128 KB
  const size_t needSplit = needKV + oPartB + lPartB;

  ushort* Kb = (ushort*)d_ws;
  ushort* Vb = Kb + elems;
  if (ws_size >= needSplit) {
    float* Opart = (float*)((char*)d_ws + needKV);
    float* lpart = (float*)((char*)d_ws + needKV + oPartB);
    prep<<<dim3(512), dim3(256), 0, stream>>>(K, V, Kb, Vb);
    attn_split<<<dim3(512), dim3(512), 0, stream>>>(Q, Kb, Vb, O, Opart, lpart);
    combine<<<dim3(256), dim3(256), 0, stream>>>(Opart, lpart, O);
  } else {
    prep<<<dim3(512), dim3(256), 0, stream>>>(K, V, Kb, Vb);
    attn_fwd4<<<dim3(512), dim3(512), 0, stream>>>(Q, Kb, Vb, O);
  }
}

// Round 8
// 64.362 us; speedup vs baseline: 1.1590x; 1.1590x over previous
//
#include <hip/hip_runtime.h>
#include <hip/hip_bf16.h>

// Causal MHA forward: S=2048, H=16, D=128, fp32 in/out, bf16 MFMA internally.
// Prepass: K -> bf16 [h][s][d], V -> bf16 transposed [h][d][s] into d_ws.
// Main: 256 uniform blocks (h x pair j), each runs tile qtA=31-j then qtB=j
// (33 chunks). 8 waves = 2qf(32q) x 4kh/4dh. Proven round-5 chunk body
// (swapped QK^T, LDS-P round trip, K=32 PV). NEW: raw s_barrier + counted
// vmcnt(4) (3-buffer, 2-deep prefetch) -- no vmcnt(0) drain in the loop.
#define S_LEN 2048
#define NH 16
#define HD 128
#define KBLK 64
#define SM_BOUND 14.0f

typedef short short8 __attribute__((ext_vector_type(8)));
typedef float f32x4 __attribute__((ext_vector_type(4)));

__device__ __forceinline__ ushort f2bf(float f) {
  union { float f; unsigned u; } v; v.f = f;
  unsigned u = v.u;
  return (ushort)((u + 0x7fffu + ((u >> 16) & 1u)) >> 16);  // RNE
}

// global (AS1) -> LDS (AS3) direct 16B load; source pre-swizzled, dest linear.
#define GLDS(gp, lp)                                                      \
  __builtin_amdgcn_global_load_lds(                                       \
      (const __attribute__((address_space(1))) void*)(gp),                \
      (__attribute__((address_space(3))) void*)(lp), 16, 0, 0)

// ---------------- prepass: convert + transpose (proven r2-r6) ----------------
__global__ __launch_bounds__(256)
void prep(const float* __restrict__ Kg, const float* __restrict__ Vg,
          ushort* __restrict__ Kb, ushort* __restrict__ Vb) {
  __shared__ ushort lt[64 * HD];  // 16 KB, swizzled
  const int tid = threadIdx.x;
  const int h = blockIdx.x & 15;
  const int j0 = (blockIdx.x >> 4) * 64;

#pragma unroll
  for (int it = 0; it < 8; ++it) {
    int flat = it * 256 + tid;       // float4 index over 64x32
    int r = flat >> 5, d4 = (flat & 31) * 4;
    float4 v = *(const float4*)(Kg + ((size_t)(j0 + r) * NH + h) * HD + d4);
    ushort4 b;
    b.x = f2bf(v.x); b.y = f2bf(v.y); b.z = f2bf(v.z); b.w = f2bf(v.w);
    *(ushort4*)(Kb + ((size_t)h * S_LEN + j0 + r) * HD + d4) = b;
  }
#pragma unroll
  for (int it = 0; it < 8; ++it) {
    int flat = it * 256 + tid;
    int r = flat >> 5, d4 = (flat & 31) * 4;
    float4 v = *(const float4*)(Vg + ((size_t)(j0 + r) * NH + h) * HD + d4);
    ushort4 b;
    b.x = f2bf(v.x); b.y = f2bf(v.y); b.z = f2bf(v.z); b.w = f2bf(v.w);
    *(ushort4*)(&lt[r * 128 + (d4 ^ ((r & 7) << 3))]) = b;
  }
  __syncthreads();
  const int d = tid >> 1, half = tid & 1;
  ushort vals[32];
#pragma unroll
  for (int j = 0; j < 32; ++j) {
    int jjj = half * 32 + j;
    vals[j] = lt[jjj * 128 + (d ^ ((jjj & 7) << 3))];
  }
  ushort* dst = Vb + ((size_t)h * HD + d) * S_LEN + j0 + half * 32;
#pragma unroll
  for (int q = 0; q < 4; ++q) {
    short8 w;
#pragma unroll
    for (int e = 0; e < 8; ++e) w[e] = (short)vals[q * 8 + e];
    *(short8*)(dst + q * 8) = w;
  }
}

// ---------------- main: uniform 33-chunk blocks, async raw-barrier pipeline ----------------
__global__ __launch_bounds__(512, 2)
void attn_fwd6(const float* __restrict__ Qg, const ushort* __restrict__ Kb,
               const ushort* __restrict__ Vb, float* __restrict__ Og) {
  __shared__ ushort lds_k[3][KBLK * HD];    // 3 x 16 KB, [64 k][128 d] swizzled
  __shared__ ushort lds_vt[3][HD * KBLK];   // 3 x 16 KB, [128 d][64 k] swizzled
  __shared__ ushort lds_p[64 * 64];         // 8 KB, [64 q][64 k] swizzled
  __shared__ float  lsc[2][4][2][16];       // l partials [qf][kh][qc][lr]

  const int tid = threadIdx.x;
  const int l   = tid & 63;
  const int wv  = tid >> 6;      // 0..7
  const int qf  = wv >> 2;       // 0..1: 32-q group (both phases)
  const int kh  = wv & 3;        // phase A: 16-k quarter
  const int dh  = wv & 3;        // phase B: 32-d quarter
  const int lr  = l & 15;
  const int lg  = l >> 4;

  const int bid = blockIdx.x;
  const int h   = bid & 15;
  const int jj  = bid >> 4;      // 0..15
  const int qtA = 31 - jj;       // 16..31
  const int qbA = qtA * 64, qbB = jj * 64;

  const ushort* khp = Kb + (size_t)h * S_LEN * HD;
  const ushort* vhp = Vb + (size_t)h * HD * S_LEN;

  // staging offsets (pre-swizzled global source, linear LDS dest; rule #21)
  const int b0 = tid, b1 = 512 + tid;
  const int r0 = b0 >> 4, r1 = b1 >> 4;
  const int koff0 = r0 * 128 + (((b0 & 15) ^ (r0 & 7)) << 3);
  const int koff1 = r1 * 128 + (((b1 & 15) ^ (r1 & 7)) << 3);
  const int dd0 = b0 >> 3, dd1 = b1 >> 3;
  const int voff0 = dd0 * S_LEN + (((b0 & 7) ^ (dd0 & 7)) << 3);
  const int voff1 = dd1 * S_LEN + (((b1 & 7) ^ (dd1 & 7)) << 3);

  auto stage = [&](int buf, int kc) {
    const ushort* kbase = khp + (size_t)kc * (KBLK * HD);
    GLDS(kbase + koff0, &lds_k[buf][tid * 8]);
    GLDS(kbase + koff1, &lds_k[buf][4096 + tid * 8]);
    const ushort* vbase = vhp + (size_t)kc * KBLK;
    GLDS(vbase + voff0, &lds_vt[buf][tid * 8]);
    GLDS(vbase + voff1, &lds_vt[buf][4096 + tid * 8]);
  };

  // Q preload for BOTH tiles (B-operand layout), scale folded in.
  const float scale = 0.08838834764831845f;  // 1/sqrt(128)
  short8 qfrA[2][4], qfrB[2][4];
  auto loadQ = [&](short8 (&dst)[2][4], int qb) {
#pragma unroll
    for (int qc = 0; qc < 2; ++qc) {
      const float* qsrc = Qg + ((size_t)(qb + qf * 32 + qc * 16 + lr) * NH + h) * HD;
#pragma unroll
      for (int dk = 0; dk < 4; ++dk) {
        float4 a = *(const float4*)(qsrc + dk * 32 + lg * 8);
        float4 b2 = *(const float4*)(qsrc + dk * 32 + lg * 8 + 4);
        short8 f;
        f[0] = (short)f2bf(a.x * scale);  f[1] = (short)f2bf(a.y * scale);
        f[2] = (short)f2bf(a.z * scale);  f[3] = (short)f2bf(a.w * scale);
        f[4] = (short)f2bf(b2.x * scale); f[5] = (short)f2bf(b2.y * scale);
        f[6] = (short)f2bf(b2.z * scale); f[7] = (short)f2bf(b2.w * scale);
        dst[qc][dk] = f;
      }
    }
  };
  loadQ(qfrA, qbA);
  loadQ(qfrB, qbB);

  f32x4 oacc[2][2];  // [qc][dt]: q = qf*32+qc*16+lg*4+i, d = dh*32+dt*16+lr
#pragma unroll
  for (int qc = 0; qc < 2; ++qc)
#pragma unroll
    for (int dt = 0; dt < 2; ++dt) oacc[qc][dt] = (f32x4){0.f, 0.f, 0.f, 0.f};
  float l_run[2] = {0.f, 0.f};

  // direct-write epilogue (round-6 proven); called uniformly.
  auto epilogue = [&](int qb) {
    float t0 = l_run[0], t1 = l_run[1];
    t0 += __shfl_xor(t0, 16, 64); t0 += __shfl_xor(t0, 32, 64);
    t1 += __shfl_xor(t1, 16, 64); t1 += __shfl_xor(t1, 32, 64);
    if (lg == 0) { lsc[qf][kh][0][lr] = t0; lsc[qf][kh][1][lr] = t1; }
    __syncthreads();
    float inv[2][4];
#pragma unroll
    for (int qc = 0; qc < 2; ++qc)
#pragma unroll
      for (int i = 0; i < 4; ++i) {
        int q15 = lg * 4 + i;
        float sl = (lsc[qf][0][qc][q15] + lsc[qf][1][qc][q15]) +
                   (lsc[qf][2][qc][q15] + lsc[qf][3][qc][q15]);
        inv[qc][i] = 1.0f / sl;
      }
#pragma unroll
    for (int qc = 0; qc < 2; ++qc)
#pragma unroll
      for (int dt = 0; dt < 2; ++dt)
#pragma unroll
        for (int i = 0; i < 4; ++i) {
          int qg = qb + qf * 32 + qc * 16 + lg * 4 + i;
          Og[((size_t)qg * NH + h) * HD + dh * 32 + dt * 16 + lr] =
              oacc[qc][dt][i] * inv[qc][i];
        }
  };

  stage(0, 0);
  stage(1, 1);  // qtA >= 16, so chunk 1 is always tile A

  for (int g = 0; g < 33; ++g) {
    // top barrier: own chunk-g loads landed (counted), then block-wide sync.
    if (g == 32) { asm volatile("s_waitcnt vmcnt(0)" ::: "memory"); }
    else         { asm volatile("s_waitcnt vmcnt(4)" ::: "memory"); }
    asm volatile("s_barrier" ::: "memory");
    if (g + 2 < 33) {
      int t = g + 2;
      stage(t % 3, (t <= qtA) ? t : (t - qtA - 1));  // prefetch flies across barriers
    }
    const int bI = g % 3;
    const ushort* lk = lds_k[bI];
    const ushort* lv = lds_vt[bI];
    const bool tB = (g > qtA);
    const int kc = tB ? (g - qtA - 1) : g;
    const int qb = tB ? qbB : qbA;

    // ---- phase A: QK^T, A=K rows (kh 16k), B=Q (2 qc) ----
    f32x4 s0 = (f32x4){0.f, 0.f, 0.f, 0.f};
    f32x4 s1 = (f32x4){0.f, 0.f, 0.f, 0.f};
    const int krow = kh * 16 + lr;
    __builtin_amdgcn_s_setprio(1);
    if (!tB) {
#pragma unroll
      for (int dk = 0; dk < 4; ++dk) {
        short8 kf = *(const short8*)&lk[krow * 128 + ((dk * 32 + lg * 8) ^ ((lr & 7) << 3))];
        s0 = __builtin_amdgcn_mfma_f32_16x16x32_bf16(kf, qfrA[0][dk], s0, 0, 0, 0);
        s1 = __builtin_amdgcn_mfma_f32_16x16x32_bf16(kf, qfrA[1][dk], s1, 0, 0, 0);
      }
    } else {
#pragma unroll
      for (int dk = 0; dk < 4; ++dk) {
        short8 kf = *(const short8*)&lk[krow * 128 + ((dk * 32 + lg * 8) ^ ((lr & 7) << 3))];
        s0 = __builtin_amdgcn_mfma_f32_16x16x32_bf16(kf, qfrB[0][dk], s0, 0, 0, 0);
        s1 = __builtin_amdgcn_mfma_f32_16x16x32_bf16(kf, qfrB[1][dk], s1, 0, 0, 0);
      }
    }
    __builtin_amdgcn_s_setprio(0);

    // ---- fixed-bound softmax; mask only on diagonal chunks ----
    float p0[4], p1[4];
    if (g == qtA || g == 32) {
      const int qg0 = qb + qf * 32 + lr;
#pragma unroll
      for (int i = 0; i < 4; ++i) {
        int kg = kc * 64 + kh * 16 + lg * 4 + i;
        float e0 = __expf(s0[i] - SM_BOUND);
        float e1 = __expf(s1[i] - SM_BOUND);
        p0[i] = (kg > qg0) ? 0.f : e0;
        p1[i] = (kg > qg0 + 16) ? 0.f : e1;
      }
    } else {
#pragma unroll
      for (int i = 0; i < 4; ++i) {
        p0[i] = __expf(s0[i] - SM_BOUND);
        p1[i] = __expf(s1[i] - SM_BOUND);
      }
    }
    l_run[0] += (p0[0] + p0[1]) + (p0[2] + p0[3]);
    l_run[1] += (p1[0] + p1[1]) + (p1[2] + p1[3]);

    // ---- P -> LDS [q][k], cvt_pk-packed b32 writes, XOR-swizzled ----
    {
      int q0 = qf * 32 + lr;
      int q1 = q0 + 16;
      unsigned w;
      asm("v_cvt_pk_bf16_f32 %0, %1, %2" : "=v"(w) : "v"(p0[0]), "v"(p0[1]));
      *(unsigned*)&lds_p[q0 * 64 + ((kh * 16 + lg * 4 + 0) ^ ((q0 & 7) << 3))] = w;
      asm("v_cvt_pk_bf16_f32 %0, %1, %2" : "=v"(w) : "v"(p0[2]), "v"(p0[3]));
      *(unsigned*)&lds_p[q0 * 64 + ((kh * 16 + lg * 4 + 2) ^ ((q0 & 7) << 3))] = w;
      asm("v_cvt_pk_bf16_f32 %0, %1, %2" : "=v"(w) : "v"(p1[0]), "v"(p1[1]));
      *(unsigned*)&lds_p[q1 * 64 + ((kh * 16 + lg * 4 + 0) ^ ((q1 & 7) << 3))] = w;
      asm("v_cvt_pk_bf16_f32 %0, %1, %2" : "=v"(w) : "v"(p1[2]), "v"(p1[3]));
      *(unsigned*)&lds_p[q1 * 64 + ((kh * 16 + lg * 4 + 2) ^ ((q1 & 7) << 3))] = w;
    }
    // mid barrier: DS-only wait -- prefetch loads stay in flight (no vmcnt).
    asm volatile("s_waitcnt lgkmcnt(0)" ::: "memory");
    asm volatile("s_barrier" ::: "memory");
    __builtin_amdgcn_sched_barrier(0);

    // ---- phase B: PV over full 64 k; wave owns (qf, dh 32d) ----
    short8 pa0[2], pa1[2];
    {
      int q0 = qf * 32 + lr;
      int q1 = q0 + 16;
      pa0[0] = *(const short8*)&lds_p[q0 * 64 + ((lg * 8) ^ ((q0 & 7) << 3))];
      pa0[1] = *(const short8*)&lds_p[q0 * 64 + ((32 + lg * 8) ^ ((q0 & 7) << 3))];
      pa1[0] = *(const short8*)&lds_p[q1 * 64 + ((lg * 8) ^ ((q1 & 7) << 3))];
      pa1[1] = *(const short8*)&lds_p[q1 * 64 + ((32 + lg * 8) ^ ((q1 & 7) << 3))];
    }
    __builtin_amdgcn_s_setprio(1);
#pragma unroll
    for (int dt = 0; dt < 2; ++dt) {
      int d = dh * 32 + dt * 16 + lr;
#pragma unroll
      for (int ks = 0; ks < 2; ++ks) {
        short8 vf = *(const short8*)&lv[d * 64 + ((ks * 32 + lg * 8) ^ ((d & 7) << 3))];
        oacc[0][dt] = __builtin_amdgcn_mfma_f32_16x16x32_bf16(pa0[ks], vf, oacc[0][dt], 0, 0, 0);
        oacc[1][dt] = __builtin_amdgcn_mfma_f32_16x16x32_bf16(pa1[ks], vf, oacc[1][dt], 0, 0, 0);
      }
    }
    __builtin_amdgcn_s_setprio(0);

    if (g == qtA) {   // tile A done: write out, reset for tile B
      epilogue(qbA);
#pragma unroll
      for (int qc = 0; qc < 2; ++qc)
#pragma unroll
        for (int dt = 0; dt < 2; ++dt) oacc[qc][dt] = (f32x4){0.f, 0.f, 0.f, 0.f};
      l_run[0] = 0.f; l_run[1] = 0.f;
    }
  }
  epilogue(qbB);
}

// ---------------- fallback (no-ws, round-2 style, fixed-bound) ----------------
__global__ __launch_bounds__(256, 2)
void attn_fwd_fb(const float* __restrict__ Qg, const float* __restrict__ Kg,
                 const float* __restrict__ Vg, float* __restrict__ Og) {
  __shared__ ushort lds_k[KBLK * HD];
  __shared__ ushort lds_vt[HD * KBLK];
  __shared__ ushort lds_p[4][16 * KBLK];

  const int tid = threadIdx.x;
  const int l  = tid & 63;
  const int wv = tid >> 6;
  const int lr = l & 15;
  const int lg = l >> 4;

  const int bid = blockIdx.x;
  const int h  = bid & 15;
  const int qi = bid >> 4;
  const int qt = (qi < 16) ? (31 - 2 * qi) : (2 * (qi - 16));
  const int qbase = qt * 64;

  short8 qf[4];
  {
    const float* qsrc = Qg + ((size_t)(qbase + wv * 16 + lr) * NH + h) * HD;
#pragma unroll
    for (int dk = 0; dk < 4; ++dk) {
      float4 a = *(const float4*)(qsrc + dk * 32 + lg * 8);
      float4 b = *(const float4*)(qsrc + dk * 32 + lg * 8 + 4);
      short8 f;
      f[0] = (short)f2bf(a.x); f[1] = (short)f2bf(a.y);
      f[2] = (short)f2bf(a.z); f[3] = (short)f2bf(a.w);
      f[4] = (short)f2bf(b.x); f[5] = (short)f2bf(b.y);
      f[6] = (short)f2bf(b.z); f[7] = (short)f2bf(b.w);
      qf[dk] = f;
    }
  }

  f32x4 oacc[8];
#pragma unroll
  for (int dt = 0; dt < 8; ++dt) oacc[dt] = (f32x4){0.f, 0.f, 0.f, 0.f};
  float l_run[4] = {0.f, 0.f, 0.f, 0.f};

  const float scale = 0.08838834764831845f;
  const int nch = qt + 1;

  for (int c = 0; c < nch; ++c) {
    const int k0 = c * KBLK;
    __syncthreads();
#pragma unroll
    for (int it = 0; it < 8; ++it) {
      int flat = (it * 256 + tid) * 4;
      int r = flat >> 7, d = flat & 127;
      float4 v = *(const float4*)(Kg + ((size_t)(k0 + r) * NH + h) * HD + d);
      int idx = (r * 128 + d) ^ ((r & 7) << 3);
      ushort4 b4;
      b4.x = f2bf(v.x); b4.y = f2bf(v.y); b4.z = f2bf(v.z); b4.w = f2bf(v.w);
      *(ushort4*)&lds_k[idx] = b4;
    }
#pragma unroll
    for (int it = 0; it < 8; ++it) {
      int d0 = wv * 32 + it * 4;
      float4 v = *(const float4*)(Vg + ((size_t)(k0 + l) * NH + h) * HD + d0);
      lds_vt[((d0 + 0) * 64 + l) ^ (((d0 + 0) & 7) << 3)] = f2bf(v.x);
      lds_vt[((d0 + 1) * 64 + l) ^ (((d0 + 1) & 7) << 3)] = f2bf(v.y);
      lds_vt[((d0 + 2) * 64 + l) ^ (((d0 + 2) & 7) << 3)] = f2bf(v.z);
      lds_vt[((d0 + 3) * 64 + l) ^ (((d0 + 3) & 7) << 3)] = f2bf(v.w);
    }
    __syncthreads();

    f32x4 sacc[4];
#pragma unroll
    for (int kc = 0; kc < 4; ++kc) {
      sacc[kc] = (f32x4){0.f, 0.f, 0.f, 0.f};
#pragma unroll
      for (int dk = 0; dk < 4; ++dk) {
        int row = kc * 16 + lr;
        int idx = (row * 128 + dk * 32 + lg * 8) ^ ((row & 7) << 3);
        short8 kf = *(const short8*)&lds_k[idx];
        sacc[kc] = __builtin_amdgcn_mfma_f32_16x16x32_bf16(qf[dk], kf, sacc[kc], 0, 0, 0);
      }
    }

    float p[4][4];
    if (c == qt) {
#pragma unroll
      for (int i = 0; i < 4; ++i) {
        int qg = qbase + wv * 16 + lg * 4 + i;
#pragma unroll
        for (int kc = 0; kc < 4; ++kc) {
          float e = __expf(sacc[kc][i] * scale - SM_BOUND);
          p[kc][i] = (k0 + kc * 16 + lr > qg) ? 0.f : e;
        }
      }
    } else {
#pragma unroll
      for (int i = 0; i < 4; ++i)
#pragma unroll
        for (int kc = 0; kc < 4; ++kc)
          p[kc][i] = __expf(sacc[kc][i] * scale - SM_BOUND);
    }
#pragma unroll
    for (int i = 0; i < 4; ++i)
      l_run[i] += (p[0][i] + p[1][i]) + (p[2][i] + p[3][i]);

#pragma unroll
    for (int kc = 0; kc < 4; ++kc)
#pragma unroll
      for (int i = 0; i < 4; ++i) {
        int row = lg * 4 + i, col = kc * 16 + lr;
        lds_p[wv][(row * 64 + col) ^ ((row & 7) << 3)] = f2bf(p[kc][i]);
      }
    asm volatile("s_waitcnt lgkmcnt(0)" ::: "memory");
    __builtin_amdgcn_sched_barrier(0);

    short8 pa[2];
#pragma unroll
    for (int ks = 0; ks < 2; ++ks) {
      int idx = (lr * 64 + ks * 32 + lg * 8) ^ ((lr & 7) << 3);
      pa[ks] = *(const short8*)&lds_p[wv][idx];
    }

#pragma unroll
    for (int dt = 0; dt < 8; ++dt) {
#pragma unroll
      for (int ks = 0; ks < 2; ++ks) {
        int d = dt * 16 + lr;
        int idx = (d * 64 + ks * 32 + lg * 8) ^ ((d & 7) << 3);
        short8 vf = *(const short8*)&lds_vt[idx];
        oacc[dt] = __builtin_amdgcn_mfma_f32_16x16x32_bf16(pa[ks], vf, oacc[dt], 0, 0, 0);
      }
    }
  }

#pragma unroll
  for (int mk = 1; mk <= 8; mk <<= 1)
#pragma unroll
    for (int i = 0; i < 4; ++i)
      l_run[i] += __shfl_xor(l_run[i], mk, 64);
  float inv[4];
#pragma unroll
  for (int i = 0; i < 4; ++i) inv[i] = 1.0f / l_run[i];
#pragma unroll
  for (int dt = 0; dt < 8; ++dt)
#pragma unroll
    for (int i = 0; i < 4; ++i) {
      int qg = qbase + wv * 16 + lg * 4 + i;
      Og[((size_t)qg * NH + h) * HD + dt * 16 + lr] = oacc[dt][i] * inv[i];
    }
}

extern "C" void kernel_launch(void* const* d_in, const int* in_sizes, int n_in,
                              void* d_out, int out_size, void* d_ws, size_t ws_size,
                              hipStream_t stream) {
  (void)in_sizes; (void)n_in; (void)out_size;
  const float* Q = (const float*)d_in[0];
  const float* K = (const float*)d_in[1];
  const float* V = (const float*)d_in[2];
  float* O = (float*)d_out;

  const size_t elems = (size_t)S_LEN * NH * HD;        // 4M
  const size_t need = 2 * elems * sizeof(ushort);      // 16 MB
  if (ws_size >= need) {
    ushort* Kb = (ushort*)d_ws;
    ushort* Vb = Kb + elems;
    prep<<<dim3(512), dim3(256), 0, stream>>>(K, V, Kb, Vb);
    attn_fwd6<<<dim3(256), dim3(512), 0, stream>>>(Q, Kb, Vb, O);
  } else {
    attn_fwd_fb<<<dim3(512), dim3(256), 0, stream>>>(Q, K, V, O);
  }
}